// Round 1
// baseline (5641.089 us; speedup 1.0000x reference)
//
#include <hip/hip_runtime.h>
#include <math.h>

#define BATCH 2
#define TSTEPS 8

__device__ __forceinline__ float hsig(float v) {
    return fminf(fmaxf(0.2f * v + 0.5f, 0.0f), 1.0f);
}

// Zx[bt,y,x,oc] = bias[oc] + sum_{kh,kw,ci} x[bt,y+kh-1,x+kw-1,ci] * Wx[kh,kw,ci,oc]
__global__ void conv_x_kernel(const float* __restrict__ xin, const float* __restrict__ Wx,
                              const float* __restrict__ bias, float* __restrict__ Zx,
                              int H, int W, int Ci, int Co4, int total)
{
    int idx = blockIdx.x * blockDim.x + threadIdx.x;
    if (idx >= total) return;
    int oc = idx % Co4;
    int r = idx / Co4;
    int xw = r % W; r /= W;
    int yh = r % H;
    int bt = r / H;
    float acc = bias[oc];
    for (int kh = 0; kh < 3; ++kh) {
        int yy = yh + kh - 1;
        if (yy < 0 || yy >= H) continue;
        for (int kw = 0; kw < 3; ++kw) {
            int xx = xw + kw - 1;
            if (xx < 0 || xx >= W) continue;
            const float* xp = xin + ((size_t)(bt * H + yy) * W + xx) * Ci;
            const float* wp = Wx + (size_t)((kh * 3 + kw) * Ci) * Co4 + oc;
            for (int ci = 0; ci < Ci; ++ci) {
                acc = fmaf(xp[ci], wp[(size_t)ci * Co4], acc);
            }
        }
    }
    Zx[idx] = acc;
}

// One LSTM timestep: z = Zx[t] + conv(h_prev, Wh); gates; update c,h;
// fused BN + 2x2 upsample write of h into `out`.
__global__ void step_kernel(const float* __restrict__ Zx, const float* __restrict__ Wh,
                            const float* __restrict__ hprev, float* __restrict__ hnew,
                            float* __restrict__ cst,
                            const float* __restrict__ gamma, const float* __restrict__ beta,
                            const float* __restrict__ mmean, const float* __restrict__ mvar,
                            float* __restrict__ out,
                            int H, int W, int Co, int t, int total)
{
    int idx = blockIdx.x * blockDim.x + threadIdx.x;
    if (idx >= total) return;
    int co = idx % Co;
    int r = idx / Co;
    int xw = r % W; r /= W;
    int yh = r % H;
    int b = r / H;
    int Co4 = 4 * Co;

    const float* zp = Zx + ((size_t)((b * TSTEPS + t) * H + yh) * W + xw) * Co4;
    float a0 = zp[co], a1 = zp[Co + co], a2 = zp[2 * Co + co], a3 = zp[3 * Co + co];

    for (int kh = 0; kh < 3; ++kh) {
        int yy = yh + kh - 1;
        if (yy < 0 || yy >= H) continue;
        for (int kw = 0; kw < 3; ++kw) {
            int xx = xw + kw - 1;
            if (xx < 0 || xx >= W) continue;
            const float* hp = hprev + ((size_t)(b * H + yy) * W + xx) * Co;
            const float* wp = Wh + (size_t)((kh * 3 + kw) * Co) * Co4 + co;
            for (int ci = 0; ci < Co; ++ci) {
                float hv = hp[ci];
                const float* w = wp + (size_t)ci * Co4;
                a0 = fmaf(hv, w[0], a0);
                a1 = fmaf(hv, w[Co], a1);
                a2 = fmaf(hv, w[2 * Co], a2);
                a3 = fmaf(hv, w[3 * Co], a3);
            }
        }
    }

    float iv = hsig(a0), fv = hsig(a1), gv = tanhf(a2), ov = hsig(a3);
    float cold = cst[idx];
    float cn = fv * cold + iv * gv;
    cst[idx] = cn;
    float h = ov * tanhf(cn);
    hnew[idx] = h;

    float bnv = (h - mmean[co]) * rsqrtf(mvar[co] + 1e-3f) * gamma[co] + beta[co];
    int W2 = 2 * W;
    int H2 = 2 * H;
    size_t ob = ((size_t)(b * TSTEPS + t) * H2 + 2 * yh) * W2 + 2 * xw;
    out[ob * Co + co] = bnv;
    out[(ob + 1) * Co + co] = bnv;
    out[(ob + W2) * Co + co] = bnv;
    out[(ob + W2 + 1) * Co + co] = bnv;
}

static void run_block(const float* xin, const float* Wx, const float* Wh, const float* bias,
                      const float* g, const float* be, const float* mm, const float* mv,
                      float* Zx, float* hA, float* hB, float* cbuf, float* out,
                      int Ci, int Co, int H, int W, hipStream_t stream)
{
    int Co4 = 4 * Co;
    int totalZ = BATCH * TSTEPS * H * W * Co4;
    conv_x_kernel<<<(totalZ + 255) / 256, 256, 0, stream>>>(xin, Wx, bias, Zx, H, W, Ci, Co4, totalZ);

    size_t hbytes = (size_t)BATCH * H * W * Co * sizeof(float);
    hipMemsetAsync(hA, 0, hbytes, stream);
    hipMemsetAsync(cbuf, 0, hbytes, stream);

    int totalS = BATCH * H * W * Co;
    for (int t = 0; t < TSTEPS; ++t) {
        const float* hp = (t & 1) ? hB : hA;
        float* hn = (t & 1) ? hA : hB;
        step_kernel<<<(totalS + 255) / 256, 256, 0, stream>>>(
            Zx, Wh, hp, hn, cbuf, g, be, mm, mv, out, H, W, Co, t, totalS);
    }
}

extern "C" void kernel_launch(void* const* d_in, const int* in_sizes, int n_in,
                              void* d_out, int out_size, void* d_ws, size_t ws_size,
                              hipStream_t stream) {
    const float* x   = (const float*)d_in[0];
    const float* Wx1 = (const float*)d_in[1];
    const float* Wh1 = (const float*)d_in[2];
    const float* b1  = (const float*)d_in[3];
    const float* g1  = (const float*)d_in[4];
    const float* be1 = (const float*)d_in[5];
    const float* mm1 = (const float*)d_in[6];
    const float* mv1 = (const float*)d_in[7];
    const float* Wx2 = (const float*)d_in[8];
    const float* Wh2 = (const float*)d_in[9];
    const float* b2  = (const float*)d_in[10];
    const float* g2  = (const float*)d_in[11];
    const float* be2 = (const float*)d_in[12];
    const float* mm2 = (const float*)d_in[13];
    const float* mv2 = (const float*)d_in[14];
    const float* Wx3 = (const float*)d_in[15];
    const float* Wh3 = (const float*)d_in[16];
    const float* b3  = (const float*)d_in[17];
    const float* g3  = (const float*)d_in[18];
    const float* be3 = (const float*)d_in[19];
    const float* mm3 = (const float*)d_in[20];
    const float* mv3 = (const float*)d_in[21];

    float* ws = (float*)d_ws;
    // Workspace layout (floats):
    //   Zx     : 8,388,608  (max over blocks: block3 = 2*8*64*64*128)
    //   hA     :   262,144  (max: 2*64*64*32)
    //   hB     :   262,144
    //   cbuf   :   262,144
    //   x2     : 2,097,152  (block1 out: 2*8*32*32*128)
    //   x3     : 4,194,304  (block2 out: 2*8*64*64*64)
    float* Zx   = ws;
    float* hA   = Zx + 8388608;
    float* hB   = hA + 262144;
    float* cbuf = hB + 262144;
    float* x2   = cbuf + 262144;
    float* x3   = x2 + 2097152;
    float* outp = (float*)d_out;

    // Block 1: Ci=192, Co=128, 16x16 -> out 32x32
    run_block(x,  Wx1, Wh1, b1, g1, be1, mm1, mv1, Zx, hA, hB, cbuf, x2, 192, 128, 16, 16, stream);
    // Block 2: Ci=128, Co=64, 32x32 -> out 64x64
    run_block(x2, Wx2, Wh2, b2, g2, be2, mm2, mv2, Zx, hA, hB, cbuf, x3, 128, 64, 32, 32, stream);
    // Block 3: Ci=64, Co=32, 64x64 -> out 128x128
    run_block(x3, Wx3, Wh3, b3, g3, be3, mm3, mv3, Zx, hA, hB, cbuf, outp, 64, 32, 64, 64, stream);
}

// Round 2
// 1550.431 us; speedup vs baseline: 3.6384x; 3.6384x over previous
//
#include <hip/hip_runtime.h>
#include <math.h>

#define BATCH 2
#define TSTEPS 8
#define BK 16

__device__ __forceinline__ float hsig(float v) {
    return fminf(fmaxf(0.2f * v + 0.5f, 0.0f), 1.0f);
}

// ---------------------------------------------------------------------------
// conv_x as implicit-im2col GEMM:
//   C[m, n] = bias[n] + sum_k A[m,k] * W[k,n]
//   m = bt*H*W + y*W + x  (M = B*T*H*W, multiple of 64)
//   k = (kh*3+kw)*Ci + ci (K = 9*Ci, Ci % 16 == 0 so each BK-tile has fixed kh,kw)
//   n = output channel    (N = 4*Co, multiple of 64)
// 64x64 tile, BK=16, 256 threads, 4x4 micro-tile per thread.
// ---------------------------------------------------------------------------
__global__ __launch_bounds__(256) void convx_gemm(
    const float* __restrict__ xin, const float* __restrict__ Wx,
    const float* __restrict__ bias, float* __restrict__ Zx,
    int H, int Wd, int Ci, int N, int K)
{
    __shared__ float As[BK][68];      // [ci][row], padded stride to break bank conflicts
    __shared__ float Bs[BK][64];      // [k][n]

    const int tid = threadIdx.x;
    const int m0 = blockIdx.x * 64;
    const int n0 = blockIdx.y * 64;
    const int tm = tid >> 4;          // 0..15 -> rows tm*4..tm*4+3
    const int tn = tid & 15;          // 0..15 -> cols tn*4..tn*4+3

    // A-load role (fixed per thread): row r, 4 consecutive ci starting at cj
    const int r  = tid >> 2;          // 0..63
    const int cj = (tid & 3) << 2;    // 0,4,8,12
    const int HW = H * Wd;
    const int p  = m0 + r;
    const int bt = p / HW;
    const int rem = p - bt * HW;
    const int y  = rem / Wd;
    const int x  = rem - y * Wd;

    float acc[4][4] = {};

    for (int k0 = 0; k0 < K; k0 += BK) {
        const int khkw = k0 / Ci;             // 0..8, constant within tile
        const int ci0  = k0 - khkw * Ci;
        const int kh   = khkw / 3;
        const int kw   = khkw - kh * 3;

        // --- A tile: 64 pixels x 16 ci, stored transposed ---
        const int yy = y + kh - 1, xx = x + kw - 1;
        float4 av = make_float4(0.f, 0.f, 0.f, 0.f);
        if (yy >= 0 && yy < H && xx >= 0 && xx < Wd)
            av = *(const float4*)&xin[((size_t)(bt * H + yy) * Wd + xx) * Ci + ci0 + cj];
        As[cj + 0][r] = av.x;
        As[cj + 1][r] = av.y;
        As[cj + 2][r] = av.z;
        As[cj + 3][r] = av.w;

        // --- B tile: 16 k x 64 n ---
        {
            const int kk = tid >> 4;
            const int nj = (tid & 15) << 2;
            *(float4*)&Bs[kk][nj] =
                *(const float4*)&Wx[(size_t)(k0 + kk) * N + n0 + nj];
        }
        __syncthreads();

        #pragma unroll
        for (int kk = 0; kk < BK; ++kk) {
            float4 a = *(float4*)&As[kk][tm << 2];
            float4 b = *(float4*)&Bs[kk][tn << 2];
            acc[0][0] = fmaf(a.x, b.x, acc[0][0]);
            acc[0][1] = fmaf(a.x, b.y, acc[0][1]);
            acc[0][2] = fmaf(a.x, b.z, acc[0][2]);
            acc[0][3] = fmaf(a.x, b.w, acc[0][3]);
            acc[1][0] = fmaf(a.y, b.x, acc[1][0]);
            acc[1][1] = fmaf(a.y, b.y, acc[1][1]);
            acc[1][2] = fmaf(a.y, b.z, acc[1][2]);
            acc[1][3] = fmaf(a.y, b.w, acc[1][3]);
            acc[2][0] = fmaf(a.z, b.x, acc[2][0]);
            acc[2][1] = fmaf(a.z, b.y, acc[2][1]);
            acc[2][2] = fmaf(a.z, b.z, acc[2][2]);
            acc[2][3] = fmaf(a.z, b.w, acc[2][3]);
            acc[3][0] = fmaf(a.w, b.x, acc[3][0]);
            acc[3][1] = fmaf(a.w, b.y, acc[3][1]);
            acc[3][2] = fmaf(a.w, b.z, acc[3][2]);
            acc[3][3] = fmaf(a.w, b.w, acc[3][3]);
        }
        __syncthreads();
    }

    const float4 bv = *(const float4*)&bias[n0 + (tn << 2)];
    #pragma unroll
    for (int i = 0; i < 4; ++i) {
        const int m = m0 + (tm << 2) + i;
        float4 o = make_float4(acc[i][0] + bv.x, acc[i][1] + bv.y,
                               acc[i][2] + bv.z, acc[i][3] + bv.w);
        *(float4*)&Zx[(size_t)m * N + n0 + (tn << 2)] = o;
    }
}

// ---------------------------------------------------------------------------
// One LSTM timestep as GEMM over N' = Co with 4 gate-accumulators per (m, co):
//   z_g[m, co] = Zx[zrow(m), g*Co+co] + sum_k hprev_patch[m,k] * Wh[k, g*Co+co]
// Tile: 64 pixels x 16 co (x 4 gates). Epilogue: LSTM update + BN + 2x2 upsample.
// ---------------------------------------------------------------------------
__global__ __launch_bounds__(256) void steph_gemm(
    const float* __restrict__ Zx, const float* __restrict__ Wh,
    const float* __restrict__ hprev, float* __restrict__ hnew,
    float* __restrict__ cst,
    const float* __restrict__ gamma, const float* __restrict__ beta,
    const float* __restrict__ mmean, const float* __restrict__ mvar,
    float* __restrict__ out, int H, int Wd, int Co, int t)
{
    __shared__ float As[BK][68];        // [ci][row]
    __shared__ float Bs[BK][16][4];     // [k][co][gate]

    const int tid = threadIdx.x;
    const int m0  = blockIdx.x * 64;
    const int co0 = blockIdx.y * 16;
    const int N4  = 4 * Co;
    const int K   = 9 * Co;
    const int tm  = tid >> 4;
    const int tn  = tid & 15;

    const int r  = tid >> 2;
    const int cj = (tid & 3) << 2;
    const int HW = H * Wd;
    const int p  = m0 + r;
    const int b  = p / HW;
    const int rem = p - b * HW;
    const int y  = rem / Wd;
    const int x  = rem - y * Wd;

    float acc[4][4] = {};   // [row][gate]

    for (int k0 = 0; k0 < K; k0 += BK) {
        const int khkw = k0 / Co;
        const int ci0  = k0 - khkw * Co;
        const int kh   = khkw / 3;
        const int kw   = khkw - kh * 3;

        const int yy = y + kh - 1, xx = x + kw - 1;
        float4 av = make_float4(0.f, 0.f, 0.f, 0.f);
        if (yy >= 0 && yy < H && xx >= 0 && xx < Wd)
            av = *(const float4*)&hprev[((size_t)(b * H + yy) * Wd + xx) * Co + ci0 + cj];
        As[cj + 0][r] = av.x;
        As[cj + 1][r] = av.y;
        As[cj + 2][r] = av.z;
        As[cj + 3][r] = av.w;

        {
            const int kk  = tid >> 4;
            const int idx = tid & 15;
            const int g2  = idx >> 2;          // gate
            const int j4  = (idx & 3) << 2;    // co offset
            float4 bw = *(const float4*)&Wh[(size_t)(k0 + kk) * N4 + g2 * Co + co0 + j4];
            Bs[kk][j4 + 0][g2] = bw.x;
            Bs[kk][j4 + 1][g2] = bw.y;
            Bs[kk][j4 + 2][g2] = bw.z;
            Bs[kk][j4 + 3][g2] = bw.w;
        }
        __syncthreads();

        #pragma unroll
        for (int kk = 0; kk < BK; ++kk) {
            float4 a  = *(float4*)&As[kk][tm << 2];
            float4 bq = *(float4*)&Bs[kk][tn][0];   // gates i,f,g,o for co0+tn
            acc[0][0] = fmaf(a.x, bq.x, acc[0][0]);
            acc[0][1] = fmaf(a.x, bq.y, acc[0][1]);
            acc[0][2] = fmaf(a.x, bq.z, acc[0][2]);
            acc[0][3] = fmaf(a.x, bq.w, acc[0][3]);
            acc[1][0] = fmaf(a.y, bq.x, acc[1][0]);
            acc[1][1] = fmaf(a.y, bq.y, acc[1][1]);
            acc[1][2] = fmaf(a.y, bq.z, acc[1][2]);
            acc[1][3] = fmaf(a.y, bq.w, acc[1][3]);
            acc[2][0] = fmaf(a.z, bq.x, acc[2][0]);
            acc[2][1] = fmaf(a.z, bq.y, acc[2][1]);
            acc[2][2] = fmaf(a.z, bq.z, acc[2][2]);
            acc[2][3] = fmaf(a.z, bq.w, acc[2][3]);
            acc[3][0] = fmaf(a.w, bq.x, acc[3][0]);
            acc[3][1] = fmaf(a.w, bq.y, acc[3][1]);
            acc[3][2] = fmaf(a.w, bq.z, acc[3][2]);
            acc[3][3] = fmaf(a.w, bq.w, acc[3][3]);
        }
        __syncthreads();
    }

    // Epilogue: LSTM gates + BN + 2x2 upsample
    const int co = co0 + tn;
    const float ga  = gamma[co];
    const float bb  = beta[co];
    const float mmn = mmean[co];
    const float inv = rsqrtf(mvar[co] + 1e-3f);
    const int W2 = Wd * 2;

    #pragma unroll
    for (int i = 0; i < 4; ++i) {
        const int m  = m0 + (tm << 2) + i;
        const int b2 = m / HW;
        const int yx = m - b2 * HW;
        const int y2 = yx / Wd;
        const int x2 = yx - y2 * Wd;

        const size_t zrow = (size_t)(b2 * TSTEPS + t) * HW + yx;
        const float* zp = &Zx[zrow * N4];
        const float zi = zp[co]          + acc[i][0];
        const float zf = zp[Co + co]     + acc[i][1];
        const float zg = zp[2 * Co + co] + acc[i][2];
        const float zo = zp[3 * Co + co] + acc[i][3];

        const float iv = hsig(zi), fv = hsig(zf);
        const float gv = tanhf(zg), ov = hsig(zo);
        const float cold = cst[(size_t)m * Co + co];
        const float cn = fv * cold + iv * gv;
        cst[(size_t)m * Co + co] = cn;
        const float h = ov * tanhf(cn);
        hnew[(size_t)m * Co + co] = h;

        const float bnv = (h - mmn) * inv * ga + bb;
        const size_t ob = ((size_t)(b2 * TSTEPS + t) * 2 * H + 2 * y2) * W2 + 2 * x2;
        out[ob * Co + co]            = bnv;
        out[(ob + 1) * Co + co]      = bnv;
        out[(ob + W2) * Co + co]     = bnv;
        out[(ob + W2 + 1) * Co + co] = bnv;
    }
}

static void run_block(const float* xin, const float* Wx, const float* Wh, const float* bias,
                      const float* g, const float* be, const float* mm, const float* mv,
                      float* Zx, float* hA, float* hB, float* cbuf, float* out,
                      int Ci, int Co, int H, int W, hipStream_t stream)
{
    const int N = 4 * Co;
    const int K = 9 * Ci;
    const int M = BATCH * TSTEPS * H * W;
    dim3 gridX(M / 64, N / 64);
    convx_gemm<<<gridX, 256, 0, stream>>>(xin, Wx, bias, Zx, H, W, Ci, N, K);

    const size_t hbytes = (size_t)BATCH * H * W * Co * sizeof(float);
    hipMemsetAsync(hA, 0, hbytes, stream);
    hipMemsetAsync(cbuf, 0, hbytes, stream);

    const int Ms = BATCH * H * W;
    dim3 gridS(Ms / 64, Co / 16);
    for (int t = 0; t < TSTEPS; ++t) {
        const float* hp = (t & 1) ? hB : hA;
        float* hn = (t & 1) ? hA : hB;
        steph_gemm<<<gridS, 256, 0, stream>>>(
            Zx, Wh, hp, hn, cbuf, g, be, mm, mv, out, H, W, Co, t);
    }
}

extern "C" void kernel_launch(void* const* d_in, const int* in_sizes, int n_in,
                              void* d_out, int out_size, void* d_ws, size_t ws_size,
                              hipStream_t stream) {
    const float* x   = (const float*)d_in[0];
    const float* Wx1 = (const float*)d_in[1];
    const float* Wh1 = (const float*)d_in[2];
    const float* b1  = (const float*)d_in[3];
    const float* g1  = (const float*)d_in[4];
    const float* be1 = (const float*)d_in[5];
    const float* mm1 = (const float*)d_in[6];
    const float* mv1 = (const float*)d_in[7];
    const float* Wx2 = (const float*)d_in[8];
    const float* Wh2 = (const float*)d_in[9];
    const float* b2  = (const float*)d_in[10];
    const float* g2  = (const float*)d_in[11];
    const float* be2 = (const float*)d_in[12];
    const float* mm2 = (const float*)d_in[13];
    const float* mv2 = (const float*)d_in[14];
    const float* Wx3 = (const float*)d_in[15];
    const float* Wh3 = (const float*)d_in[16];
    const float* b3  = (const float*)d_in[17];
    const float* g3  = (const float*)d_in[18];
    const float* be3 = (const float*)d_in[19];
    const float* mm3 = (const float*)d_in[20];
    const float* mv3 = (const float*)d_in[21];

    float* ws = (float*)d_ws;
    float* Zx   = ws;                 // 8,388,608 floats (max: block3)
    float* hA   = Zx + 8388608;       //   262,144
    float* hB   = hA + 262144;        //   262,144
    float* cbuf = hB + 262144;        //   262,144
    float* x2   = cbuf + 262144;      // 2,097,152 (block1 out)
    float* x3   = x2 + 2097152;       // 4,194,304 (block2 out)
    float* outp = (float*)d_out;

    run_block(x,  Wx1, Wh1, b1, g1, be1, mm1, mv1, Zx, hA, hB, cbuf, x2, 192, 128, 16, 16, stream);
    run_block(x2, Wx2, Wh2, b2, g2, be2, mm2, mv2, Zx, hA, hB, cbuf, x3, 128, 64, 32, 32, stream);
    run_block(x3, Wx3, Wh3, b3, g3, be3, mm3, mv3, Zx, hA, hB, cbuf, outp, 64, 32, 64, 64, stream);
}

// Round 4
// 566.671 us; speedup vs baseline: 9.9548x; 2.7360x over previous
//
#include <hip/hip_runtime.h>
#include <math.h>

#define BATCH 2
#define TSTEPS 8

typedef __attribute__((ext_vector_type(8))) short s16x8;   // 8 bf16 (4 VGPRs)
typedef __attribute__((ext_vector_type(4))) float f32x4;   // MFMA accum

__device__ __forceinline__ float hsig(float v){ return fminf(fmaxf(0.2f*v+0.5f,0.f),1.f); }

__device__ __forceinline__ ushort f2bf(float f){
    uint u = __builtin_bit_cast(uint, f);
    u = (u + 0x7FFFu + ((u >> 16) & 1u)) >> 16;   // round-to-nearest-even
    return (ushort)u;
}

__global__ void cast_bf16_kernel(const float* __restrict__ src, ushort* __restrict__ dst, int n){
    int i = blockIdx.x * 256 + threadIdx.x;
    if (i < n) dst[i] = f2bf(src[i]);
}

// W [K][N] fp32 -> Wt [N][K] bf16. interleave: dst row n' = co*4+g pulls src col g*Co+co.
__global__ void transw_kernel(const float* __restrict__ W, ushort* __restrict__ Wt,
                              int K, int N, int Co, int interleave){
    int i = blockIdx.x * 256 + threadIdx.x;
    if (i >= K * N) return;
    int n = i / K, k = i - n * K;
    int ns = n;
    if (interleave){ int g = n & 3, co = n >> 2; ns = g * Co + co; }
    Wt[i] = f2bf(W[(size_t)k * N + ns]);
}

// ---------------------------------------------------------------------------
// convx: implicit-im2col GEMM, bf16 MFMA. Tile 128x128, BK=32, 256 thr (4 waves 2x2).
// A[m][k]: m = pixel (bt,y,x); k = tap*Ci + ci (Ci%32==0 so tap fixed per BK tile).
// Wt is [N][K] bf16. Zx out fp32 [M][N] with bias.
// Staging: each thread loads TWO uint4 per tile (128 rows x 32 bf16 = 2 x 2048).
// ---------------------------------------------------------------------------
__global__ __launch_bounds__(256) void convx_mfma(
    const ushort* __restrict__ Abf, const ushort* __restrict__ Wt,
    const float* __restrict__ bias, float* __restrict__ Zx,
    int H, int Wd, int Ci, int N, int K)
{
    __shared__ ushort As[128 * 40];   // rows padded to 40 bf16 (80 B, 16B-aligned)
    __shared__ ushort Bs[128 * 40];

    const int tid = threadIdx.x;
    const int m0 = blockIdx.x * 128, n0 = blockIdx.y * 128;
    const int lane = tid & 63, wave = tid >> 6;
    const int wm = wave >> 1, wn = wave & 1;
    const int quad = lane >> 4, l16 = lane & 15;

    const int arow = tid >> 1;            // 0..127
    const int kbase = (tid & 1) << 3;     // 0 or 8; second chunk at +16
    const int HW = H * Wd;
    const int p = m0 + arow;
    const int bt = p / HW; const int rem = p - bt * HW;
    const int y = rem / Wd, x = rem - (rem / Wd) * Wd;

    f32x4 acc[4][4] = {};

    int tap = 0, ci0 = 0;
    for (int k0 = 0; k0 < K; k0 += 32){
        const int kh = tap / 3, kw = tap - (tap / 3) * 3;
        const int yy = y + kh - 1, xx = x + kw - 1;
        uint4 av0 = make_uint4(0u,0u,0u,0u), av1 = make_uint4(0u,0u,0u,0u);
        if (yy >= 0 && yy < H && xx >= 0 && xx < Wd){
            const ushort* ap = &Abf[((size_t)(bt * H + yy) * Wd + xx) * Ci + ci0 + kbase];
            av0 = *(const uint4*)ap;
            av1 = *(const uint4*)(ap + 16);
        }
        *(uint4*)&As[arow * 40 + kbase]      = av0;
        *(uint4*)&As[arow * 40 + kbase + 16] = av1;

        const ushort* bp = &Wt[(size_t)(n0 + arow) * K + k0 + kbase];
        *(uint4*)&Bs[arow * 40 + kbase]      = *(const uint4*)bp;
        *(uint4*)&Bs[arow * 40 + kbase + 16] = *(const uint4*)(bp + 16);
        __syncthreads();

        s16x8 af[4], bfr[4];
        #pragma unroll
        for (int mt = 0; mt < 4; ++mt)
            af[mt] = *(const s16x8*)&As[(wm * 64 + mt * 16 + l16) * 40 + quad * 8];
        #pragma unroll
        for (int nt = 0; nt < 4; ++nt)
            bfr[nt] = *(const s16x8*)&Bs[(wn * 64 + nt * 16 + l16) * 40 + quad * 8];
        #pragma unroll
        for (int mt = 0; mt < 4; ++mt)
            #pragma unroll
            for (int nt = 0; nt < 4; ++nt)
                acc[mt][nt] = __builtin_amdgcn_mfma_f32_16x16x32_bf16(af[mt], bfr[nt], acc[mt][nt], 0, 0, 0);
        __syncthreads();

        ci0 += 32; if (ci0 == Ci){ ci0 = 0; ++tap; }
    }

    #pragma unroll
    for (int mt = 0; mt < 4; ++mt){
        #pragma unroll
        for (int nt = 0; nt < 4; ++nt){
            const int col = n0 + wn * 64 + nt * 16 + l16;
            const float bv = bias[col];
            #pragma unroll
            for (int r = 0; r < 4; ++r){
                const int row = m0 + wm * 64 + mt * 16 + quad * 4 + r;
                Zx[(size_t)row * N + col] = acc[mt][nt][r] + bv;
            }
        }
    }
}

// ---------------------------------------------------------------------------
// LSTM step: z = Zx[t] + conv(h_prev, Wh) via bf16 MFMA. Tile 64x64, BK=32,
// 256 thr (4 waves 2x2, each 32x32). Wht is gate-interleaved [n'=co*4+g][K].
// Epilogue: z through LDS -> gates -> c,h update -> BN -> 2x2 upsample.
// ---------------------------------------------------------------------------
template<int OUT_BF16>
__global__ __launch_bounds__(256) void step_mfma(
    const float* __restrict__ Zx, const ushort* __restrict__ Wht,
    const ushort* __restrict__ hprev, ushort* __restrict__ hnew,
    float* __restrict__ cst,
    const float* __restrict__ gamma, const float* __restrict__ beta,
    const float* __restrict__ mmean, const float* __restrict__ mvar,
    void* __restrict__ outp, int H, int Wd, int Co, int t)
{
    __shared__ char smem[64 * 68 * 4];            // 17408 B
    ushort* As = (ushort*)smem;                   // 64*40 bf16
    ushort* Bs = (ushort*)(smem + 64 * 40 * 2);   // 64*40 bf16
    float*  Zs = (float*)smem;                    // 64*68 fp32 (after K-loop)

    const int tid = threadIdx.x;
    const int m0 = blockIdx.x * 64, n0 = blockIdx.y * 64;
    const int lane = tid & 63, wave = tid >> 6;
    const int wm = wave >> 1, wn = wave & 1;
    const int quad = lane >> 4, l16 = lane & 15;
    const int N4 = 4 * Co, K = 9 * Co;
    const int HW = H * Wd;

    const int arow = tid >> 2, aq = (tid & 3) << 3;   // 64 rows x 4 chunks of 8 bf16
    const int p = m0 + arow;
    const int b = p / HW; const int rem = p - b * HW;
    const int y = rem / Wd, x = rem - (rem / Wd) * Wd;

    f32x4 acc[2][2] = {};

    int tap = 0, ci0 = 0;
    for (int k0 = 0; k0 < K; k0 += 32){
        const int kh = tap / 3, kw = tap - (tap / 3) * 3;
        const int yy = y + kh - 1, xx = x + kw - 1;
        uint4 av = make_uint4(0u, 0u, 0u, 0u);
        if (yy >= 0 && yy < H && xx >= 0 && xx < Wd)
            av = *(const uint4*)&hprev[((size_t)(b * H + yy) * Wd + xx) * Co + ci0 + aq];
        *(uint4*)&As[arow * 40 + aq] = av;

        uint4 bv = *(const uint4*)&Wht[(size_t)(n0 + arow) * K + k0 + aq];
        *(uint4*)&Bs[arow * 40 + aq] = bv;
        __syncthreads();

        s16x8 af[2], bfr[2];
        #pragma unroll
        for (int mt = 0; mt < 2; ++mt)
            af[mt] = *(const s16x8*)&As[(wm * 32 + mt * 16 + l16) * 40 + quad * 8];
        #pragma unroll
        for (int nt = 0; nt < 2; ++nt)
            bfr[nt] = *(const s16x8*)&Bs[(wn * 32 + nt * 16 + l16) * 40 + quad * 8];
        #pragma unroll
        for (int mt = 0; mt < 2; ++mt)
            #pragma unroll
            for (int nt = 0; nt < 2; ++nt)
                acc[mt][nt] = __builtin_amdgcn_mfma_f32_16x16x32_bf16(af[mt], bfr[nt], acc[mt][nt], 0, 0, 0);
        __syncthreads();

        ci0 += 32; if (ci0 == Co){ ci0 = 0; ++tap; }
    }

    // stash z tile (local layout [pixel][co*4+g]) in LDS
    #pragma unroll
    for (int mt = 0; mt < 2; ++mt)
        #pragma unroll
        for (int nt = 0; nt < 2; ++nt)
            #pragma unroll
            for (int r = 0; r < 4; ++r)
                Zs[(wm * 32 + mt * 16 + quad * 4 + r) * 68 + wn * 32 + nt * 16 + l16] = acc[mt][nt][r];
    __syncthreads();

    const int co0 = n0 >> 2;
    #pragma unroll
    for (int it = 0; it < 4; ++it){
        const int idx = it * 256 + tid;
        const int pp = idx >> 4, lco = idx & 15;
        const int m = m0 + pp;
        const int b2 = m / HW; const int rr = m - b2 * HW;
        const int y2 = rr / Wd, x2 = rr - (rr / Wd) * Wd;
        const int co = co0 + lco;

        const float* zrowp = &Zx[((size_t)(b2 * TSTEPS + t) * HW + rr) * N4];
        const float zi = Zs[pp * 68 + lco * 4 + 0] + zrowp[co];
        const float zf = Zs[pp * 68 + lco * 4 + 1] + zrowp[Co + co];
        const float zg = Zs[pp * 68 + lco * 4 + 2] + zrowp[2 * Co + co];
        const float zo = Zs[pp * 68 + lco * 4 + 3] + zrowp[3 * Co + co];

        const float iv = hsig(zi), fv = hsig(zf);
        const float gv = tanhf(zg), ov = hsig(zo);
        const float cold = cst[(size_t)m * Co + co];
        const float cn = fv * cold + iv * gv;
        cst[(size_t)m * Co + co] = cn;
        const float h = ov * tanhf(cn);
        hnew[(size_t)m * Co + co] = f2bf(h);

        const float bnv = (h - mmean[co]) * rsqrtf(mvar[co] + 1e-3f) * gamma[co] + beta[co];
        const int W2 = 2 * Wd;
        const size_t ob = ((size_t)(b2 * TSTEPS + t) * 2 * H + 2 * y2) * W2 + 2 * x2;
        if (OUT_BF16){
            ushort* o = (ushort*)outp; const ushort hv = f2bf(bnv);
            o[ob * Co + co] = hv; o[(ob + 1) * Co + co] = hv;
            o[(ob + W2) * Co + co] = hv; o[(ob + W2 + 1) * Co + co] = hv;
        } else {
            float* o = (float*)outp;
            o[ob * Co + co] = bnv; o[(ob + 1) * Co + co] = bnv;
            o[(ob + W2) * Co + co] = bnv; o[(ob + W2 + 1) * Co + co] = bnv;
        }
    }
}

static void run_block(const ushort* xbf, const ushort* Wxt, const ushort* Wht, const float* bias,
                      const float* g, const float* be, const float* mm, const float* mv,
                      float* Zx, ushort* hA, ushort* hB, float* cbuf, void* out, int out_bf16,
                      int Ci, int Co, int H, int W, hipStream_t stream)
{
    const int N = 4 * Co, K = 9 * Ci;
    const int M = BATCH * TSTEPS * H * W;
    dim3 gx(M / 128, N / 128);
    convx_mfma<<<gx, 256, 0, stream>>>(xbf, Wxt, bias, Zx, H, W, Ci, N, K);

    hipMemsetAsync(hA, 0, (size_t)BATCH * H * W * Co * sizeof(ushort), stream);
    hipMemsetAsync(cbuf, 0, (size_t)BATCH * H * W * Co * sizeof(float), stream);

    const int Ms = BATCH * H * W;
    dim3 gs(Ms / 64, N / 64);
    for (int t = 0; t < TSTEPS; ++t){
        const ushort* hp = (t & 1) ? hB : hA;
        ushort* hn = (t & 1) ? hA : hB;
        if (out_bf16)
            step_mfma<1><<<gs, 256, 0, stream>>>(Zx, Wht, hp, hn, cbuf, g, be, mm, mv, out, H, W, Co, t);
        else
            step_mfma<0><<<gs, 256, 0, stream>>>(Zx, Wht, hp, hn, cbuf, g, be, mm, mv, out, H, W, Co, t);
    }
}

extern "C" void kernel_launch(void* const* d_in, const int* in_sizes, int n_in,
                              void* d_out, int out_size, void* d_ws, size_t ws_size,
                              hipStream_t stream) {
    const float* x   = (const float*)d_in[0];
    const float* Wx1 = (const float*)d_in[1];  const float* Wh1 = (const float*)d_in[2];
    const float* b1  = (const float*)d_in[3];  const float* g1  = (const float*)d_in[4];
    const float* be1 = (const float*)d_in[5];  const float* mm1 = (const float*)d_in[6];
    const float* mv1 = (const float*)d_in[7];
    const float* Wx2 = (const float*)d_in[8];  const float* Wh2 = (const float*)d_in[9];
    const float* b2  = (const float*)d_in[10]; const float* g2  = (const float*)d_in[11];
    const float* be2 = (const float*)d_in[12]; const float* mm2 = (const float*)d_in[13];
    const float* mv2 = (const float*)d_in[14];
    const float* Wx3 = (const float*)d_in[15]; const float* Wh3 = (const float*)d_in[16];
    const float* b3  = (const float*)d_in[17]; const float* g3  = (const float*)d_in[18];
    const float* be3 = (const float*)d_in[19]; const float* mm3 = (const float*)d_in[20];
    const float* mv3 = (const float*)d_in[21];

    char* ws = (char*)d_ws;
    size_t off = 0;
    auto alloc = [&](size_t bytes) { char* p = ws + off; off += (bytes + 255) & ~(size_t)255; return p; };

    float*  Zx   = (float*)alloc(8388608ull * 4);      // max Zx (block3: 65536*128)
    float*  cbuf = (float*)alloc(262144ull * 4);       // max c (block3: 8192*32)
    ushort* xbf  = (ushort*)alloc(786432ull * 2);      // x cast
    ushort* x2   = (ushort*)alloc(2097152ull * 2);     // block1 out (bf16)
    ushort* x3   = (ushort*)alloc(4194304ull * 2);     // block2 out (bf16)
    ushort* hA   = (ushort*)alloc(262144ull * 2);
    ushort* hB   = (ushort*)alloc(262144ull * 2);
    ushort* Wxt1 = (ushort*)alloc(884736ull * 2);
    ushort* Wxt2 = (ushort*)alloc(294912ull * 2);
    ushort* Wxt3 = (ushort*)alloc(73728ull * 2);
    ushort* Wht1 = (ushort*)alloc(589824ull * 2);
    ushort* Wht2 = (ushort*)alloc(147456ull * 2);
    ushort* Wht3 = (ushort*)alloc(36864ull * 2);

    // prep: casts + weight transposes
    cast_bf16_kernel<<<(786432 + 255) / 256, 256, 0, stream>>>(x, xbf, 786432);
    transw_kernel<<<(884736 + 255) / 256, 256, 0, stream>>>(Wx1, Wxt1, 1728, 512, 128, 0);
    transw_kernel<<<(294912 + 255) / 256, 256, 0, stream>>>(Wx2, Wxt2, 1152, 256, 64, 0);
    transw_kernel<<<(73728  + 255) / 256, 256, 0, stream>>>(Wx3, Wxt3,  576, 128, 32, 0);
    transw_kernel<<<(589824 + 255) / 256, 256, 0, stream>>>(Wh1, Wht1, 1152, 512, 128, 1);
    transw_kernel<<<(147456 + 255) / 256, 256, 0, stream>>>(Wh2, Wht2,  576, 256, 64, 1);
    transw_kernel<<<(36864  + 255) / 256, 256, 0, stream>>>(Wh3, Wht3,  288, 128, 32, 1);

    run_block(xbf, Wxt1, Wht1, b1, g1, be1, mm1, mv1, Zx, hA, hB, cbuf, x2, 1, 192, 128, 16, 16, stream);
    run_block(x2,  Wxt2, Wht2, b2, g2, be2, mm2, mv2, Zx, hA, hB, cbuf, x3, 1, 128,  64, 32, 32, stream);
    run_block(x3,  Wxt3, Wht3, b3, g3, be3, mm3, mv3, Zx, hA, hB, cbuf, d_out, 0, 64, 32, 64, 64, stream);
}